// Round 1
// baseline (2348.113 us; speedup 1.0000x reference)
//
#include <hip/hip_runtime.h>
#include <cstddef>
#include <cstdint>

// ---------------------------------------------------------------------------
// SAGE_89429809037918: pre-Linear(128->128) -> SAGEConv(128->256)+ReLU
//   -> SAGEConv(256->256)+ReLU -> SAGEConv(256->256) -> row L2-normalize.
// Round 0: correctness-first fp32. Atomic scatter-mean; 64x64 LDS-tiled GEMM.
// ---------------------------------------------------------------------------

__global__ __launch_bounds__(256) void deg_kernel(const int* __restrict__ dst,
                                                  float* __restrict__ deg, int E) {
    int e = blockIdx.x * 256 + threadIdx.x;
    if (e < E) atomicAdd(&deg[dst[e]], 1.0f);
}

__global__ __launch_bounds__(256) void inv_kernel(const float* __restrict__ deg,
                                                  float* __restrict__ inv, int n) {
    int i = blockIdx.x * 256 + threadIdx.x;
    if (i < n) inv[i] = 1.0f / fmaxf(deg[i], 1.0f);
}

// agg[dst[e]][f] += h[src[e]][f], one thread per (edge, feature)
template <int LOGD>
__global__ __launch_bounds__(256) void scatter_kernel(const float* __restrict__ h,
                                                      const int* __restrict__ src,
                                                      const int* __restrict__ dst,
                                                      float* __restrict__ agg, int E) {
    const int D = 1 << LOGD;
    long long idx = (long long)blockIdx.x * 256 + threadIdx.x;
    if (idx >= (long long)E * D) return;
    int e = (int)(idx >> LOGD);
    int f = (int)idx & (D - 1);
    atomicAdd(&agg[(size_t)dst[e] * D + f], h[(size_t)src[e] * D + f]);
}

// out[m][n] = act( (A1[m,:]*scale_m) @ W1 + bias + A2[m,:] @ W2 )
// A1 scaled per-row by inv[m] if inv != nullptr. A2/W2 optional.
// K multiple of 16, Nn multiple of 64. Tile 64x64, 256 threads, 4x4 microtile.
__global__ __launch_bounds__(256) void gemm_sage(const float* __restrict__ A1,
                                                 const float* __restrict__ inv,
                                                 const float* __restrict__ A2,
                                                 const float* __restrict__ W1,
                                                 const float* __restrict__ bias,
                                                 const float* __restrict__ W2,
                                                 float* __restrict__ out,
                                                 int M, int K, int Nn, int relu) {
    __shared__ __align__(16) float As[16][68];  // As[k][m], stride 68 keeps float4 align
    __shared__ __align__(16) float Bs[16][64];  // Bs[k][n]

    const int t  = threadIdx.x;
    const int tx = t & 15;      // col group (4 cols each)
    const int ty = t >> 4;      // row group (4 rows each)
    const int m0 = blockIdx.x * 64;
    const int n0 = blockIdx.y * 64;

    // loader layout
    const int lrow = t >> 2;           // A tile row 0..63
    const int lk4  = (t & 3) << 2;     // A k offset {0,4,8,12}
    const int brow = t >> 4;           // B tile k 0..15
    const int bcol = (t & 15) << 2;    // B col {0,4,...,60}

    float c[4][4] = {};

    for (int pass = 0; pass < 2; ++pass) {
        const float* A = (pass == 0) ? A1 : A2;
        const float* W = (pass == 0) ? W1 : W2;
        if (pass == 1 && A2 == nullptr) break;
        const bool scaled = (pass == 0) && (inv != nullptr);

        for (int k0 = 0; k0 < K; k0 += 16) {
            // stage A (64 rows x 16 k), transposed into LDS
            {
                int gm = m0 + lrow;
                float4 v = make_float4(0.f, 0.f, 0.f, 0.f);
                if (gm < M) {
                    v = *(const float4*)(A + (size_t)gm * K + k0 + lk4);
                    if (scaled) {
                        float s = inv[gm];
                        v.x *= s; v.y *= s; v.z *= s; v.w *= s;
                    }
                }
                As[lk4 + 0][lrow] = v.x;
                As[lk4 + 1][lrow] = v.y;
                As[lk4 + 2][lrow] = v.z;
                As[lk4 + 3][lrow] = v.w;
            }
            // stage B (16 k x 64 cols)
            {
                float4 v = *(const float4*)(W + (size_t)(k0 + brow) * Nn + n0 + bcol);
                *(float4*)&Bs[brow][bcol] = v;
            }
            __syncthreads();
#pragma unroll
            for (int kk = 0; kk < 16; ++kk) {
                float4 a = *(const float4*)&As[kk][ty << 2];
                float4 b = *(const float4*)&Bs[kk][tx << 2];
                c[0][0] = fmaf(a.x, b.x, c[0][0]);
                c[0][1] = fmaf(a.x, b.y, c[0][1]);
                c[0][2] = fmaf(a.x, b.z, c[0][2]);
                c[0][3] = fmaf(a.x, b.w, c[0][3]);
                c[1][0] = fmaf(a.y, b.x, c[1][0]);
                c[1][1] = fmaf(a.y, b.y, c[1][1]);
                c[1][2] = fmaf(a.y, b.z, c[1][2]);
                c[1][3] = fmaf(a.y, b.w, c[1][3]);
                c[2][0] = fmaf(a.z, b.x, c[2][0]);
                c[2][1] = fmaf(a.z, b.y, c[2][1]);
                c[2][2] = fmaf(a.z, b.z, c[2][2]);
                c[2][3] = fmaf(a.z, b.w, c[2][3]);
                c[3][0] = fmaf(a.w, b.x, c[3][0]);
                c[3][1] = fmaf(a.w, b.y, c[3][1]);
                c[3][2] = fmaf(a.w, b.z, c[3][2]);
                c[3][3] = fmaf(a.w, b.w, c[3][3]);
            }
            __syncthreads();
        }
    }

    // epilogue
    float4 bv = make_float4(0.f, 0.f, 0.f, 0.f);
    if (bias != nullptr) bv = *(const float4*)(bias + n0 + (tx << 2));
#pragma unroll
    for (int i = 0; i < 4; ++i) {
        int gm = m0 + (ty << 2) + i;
        if (gm >= M) continue;
        float4 r;
        r.x = c[i][0] + bv.x;
        r.y = c[i][1] + bv.y;
        r.z = c[i][2] + bv.z;
        r.w = c[i][3] + bv.w;
        if (relu) {
            r.x = fmaxf(r.x, 0.f);
            r.y = fmaxf(r.y, 0.f);
            r.z = fmaxf(r.z, 0.f);
            r.w = fmaxf(r.w, 0.f);
        }
        *(float4*)(out + (size_t)gm * Nn + n0 + (tx << 2)) = r;
    }
}

// row-wise L2 normalize, rows of 256 floats; 4 rows per 256-thread block
__global__ __launch_bounds__(256) void norm_kernel(float* __restrict__ out, int M) {
    int row  = blockIdx.x * 4 + (threadIdx.x >> 6);
    int lane = threadIdx.x & 63;
    if (row >= M) return;
    float4 v = *(float4*)(out + (size_t)row * 256 + (lane << 2));
    float s = v.x * v.x + v.y * v.y + v.z * v.z + v.w * v.w;
#pragma unroll
    for (int off = 32; off > 0; off >>= 1) s += __shfl_down(s, off);
    s = __shfl(s, 0);
    float scale = 1.0f / fmaxf(sqrtf(s), 1e-12f);
    v.x *= scale; v.y *= scale; v.z *= scale; v.w *= scale;
    *(float4*)(out + (size_t)row * 256 + (lane << 2)) = v;
}

extern "C" void kernel_launch(void* const* d_in, const int* in_sizes, int n_in,
                              void* d_out, int out_size, void* d_ws, size_t ws_size,
                              hipStream_t stream) {
    const int N = 50000;
    const int E = 800000;

    const float* x     = (const float*)d_in[0];
    const int*   ei    = (const int*)d_in[1];
    const float* pre_W = (const float*)d_in[2];
    const float* pre_b = (const float*)d_in[3];
    const float* W1_l  = (const float*)d_in[4];
    const float* b1    = (const float*)d_in[5];
    const float* W1_r  = (const float*)d_in[6];
    const float* W2_l  = (const float*)d_in[7];
    const float* b2    = (const float*)d_in[8];
    const float* W2_r  = (const float*)d_in[9];
    const float* W3_l  = (const float*)d_in[10];
    const float* b3    = (const float*)d_in[11];
    const float* W3_r  = (const float*)d_in[12];
    float* out = (float*)d_out;

    const int* src = ei;
    const int* dst = ei + E;

    // workspace layout (floats): deg[N] | inv[N] | regAB[N*256] | regC[N*256] | regD[N*256]
    float* deg   = (float*)d_ws;
    float* inv   = deg + N;
    float* regAB = inv + N;                 // h0 (N*128) + agg1 (N*128); later agg2 (N*256)
    float* regC  = regAB + (size_t)N * 256; // h1; later agg3
    float* regD  = regC + (size_t)N * 256;  // h2

    float* h0   = regAB;
    float* agg1 = regAB + (size_t)N * 128;
    float* agg2 = regAB;
    float* agg3 = regC;
    float* h1   = regC;
    float* h2   = regD;

    // 1. degree + reciprocal
    hipMemsetAsync(deg, 0, (size_t)N * sizeof(float), stream);
    deg_kernel<<<(E + 255) / 256, 256, 0, stream>>>(dst, deg, E);
    inv_kernel<<<(N + 255) / 256, 256, 0, stream>>>(deg, inv, N);

    const int MT = (N + 63) / 64;  // 782 M-tiles

    // 2. pre: h0 = x @ pre_W + pre_b   [N,128]
    gemm_sage<<<dim3(MT, 2), 256, 0, stream>>>(x, nullptr, nullptr, pre_W, pre_b,
                                               nullptr, h0, N, 128, 128, 0);

    // 3. layer 1: agg1 = scatter(h0); h1 = relu(mean1@W1_l + b1 + h0@W1_r)
    hipMemsetAsync(agg1, 0, (size_t)N * 128 * sizeof(float), stream);
    scatter_kernel<7><<<(int)(((long long)E * 128 + 255) / 256), 256, 0, stream>>>(
        h0, src, dst, agg1, E);
    gemm_sage<<<dim3(MT, 4), 256, 0, stream>>>(agg1, inv, h0, W1_l, b1, W1_r,
                                               h1, N, 128, 256, 1);

    // 4. layer 2
    hipMemsetAsync(agg2, 0, (size_t)N * 256 * sizeof(float), stream);
    scatter_kernel<8><<<(int)(((long long)E * 256 + 255) / 256), 256, 0, stream>>>(
        h1, src, dst, agg2, E);
    gemm_sage<<<dim3(MT, 4), 256, 0, stream>>>(agg2, inv, h1, W2_l, b2, W2_r,
                                               h2, N, 256, 256, 1);

    // 5. layer 3 (no relu), straight into d_out
    hipMemsetAsync(agg3, 0, (size_t)N * 256 * sizeof(float), stream);
    scatter_kernel<8><<<(int)(((long long)E * 256 + 255) / 256), 256, 0, stream>>>(
        h2, src, dst, agg3, E);
    gemm_sage<<<dim3(MT, 4), 256, 0, stream>>>(agg3, inv, h2, W3_l, b3, W3_r,
                                               out, N, 256, 256, 0);

    // 6. row-wise L2 normalize
    norm_kernel<<<(N + 3) / 4, 256, 0, stream>>>(out, N);
}

// Round 2
// 1027.470 us; speedup vs baseline: 2.2853x; 2.2853x over previous
//
#include <hip/hip_runtime.h>
#include <cstddef>
#include <cstdint>

// ---------------------------------------------------------------------------
// SAGE_89429809037918: pre-Linear(128->128) -> SAGEConv(128->256)+ReLU
//   -> SAGEConv(256->256)+ReLU -> SAGEConv(256->256) -> row L2-normalize.
// R1: CSR counting-sort + wave-per-node gather aggregation (replaces atomic
//     scatter, which was atomic-RMW bound: 800 MB WRITE_SIZE, 22% HBM, 13% VALU).
// ---------------------------------------------------------------------------

// ---------------- counting sort: histogram -> scan -> fill ----------------

__global__ __launch_bounds__(256) void deg_kernel(const int* __restrict__ dst,
                                                  int* __restrict__ deg, int E) {
    int e = blockIdx.x * 256 + threadIdx.x;
    if (e < E) atomicAdd(&deg[dst[e]], 1);
}

// per-block (256-elem chunk) sums of deg
__global__ __launch_bounds__(256) void bsum_kernel(const int* __restrict__ deg,
                                                   int* __restrict__ bsum, int n) {
    int i = blockIdx.x * 256 + threadIdx.x;
    int v = (i < n) ? deg[i] : 0;
#pragma unroll
    for (int s = 32; s > 0; s >>= 1) v += __shfl_down(v, s);
    __shared__ int ws[4];
    int lane = threadIdx.x & 63, w = threadIdx.x >> 6;
    if (lane == 0) ws[w] = v;
    __syncthreads();
    if (threadIdx.x == 0) bsum[blockIdx.x] = ws[0] + ws[1] + ws[2] + ws[3];
}

// single-block exclusive scan of bsum[nb] -> boff[nb]; also off[n] = E
__global__ __launch_bounds__(256) void bscan_kernel(const int* __restrict__ bsum,
                                                    int* __restrict__ boff,
                                                    int* __restrict__ off,
                                                    int nb, int n, int E) {
    int t = threadIdx.x;
    int v = (t < nb) ? bsum[t] : 0;
    int incl = v;
#pragma unroll
    for (int s = 1; s < 64; s <<= 1) {
        int u = __shfl_up(incl, s);
        if ((t & 63) >= s) incl += u;
    }
    __shared__ int ws[4];
    int lane = t & 63, w = t >> 6;
    if (lane == 63) ws[w] = incl;
    __syncthreads();
    int woff = 0;
    for (int j = 0; j < w; ++j) woff += ws[j];
    if (t < nb) boff[t] = woff + incl - v;
    if (t == 0) off[n] = E;
}

// final: off[i] = boff[b] + exclusive_scan_within_block(deg); inv[i] = 1/max(deg,1)
__global__ __launch_bounds__(256) void scan_kernel(const int* __restrict__ deg,
                                                   const int* __restrict__ boff,
                                                   int* __restrict__ off,
                                                   float* __restrict__ inv, int n) {
    int i = blockIdx.x * 256 + threadIdx.x;
    int v = (i < n) ? deg[i] : 0;
    int incl = v;
#pragma unroll
    for (int s = 1; s < 64; s <<= 1) {
        int u = __shfl_up(incl, s);
        if ((threadIdx.x & 63) >= s) incl += u;
    }
    __shared__ int ws[4];
    int lane = threadIdx.x & 63, w = threadIdx.x >> 6;
    if (lane == 63) ws[w] = incl;
    __syncthreads();
    int woff = 0;
    for (int j = 0; j < w; ++j) woff += ws[j];
    if (i < n) {
        off[i] = boff[blockIdx.x] + woff + incl - v;
        inv[i] = 1.0f / fmaxf((float)v, 1.0f);
    }
}

// fill sorted src lists; consumes deg (counts down to 0). Order within a
// bucket is arbitrary (sum order nondeterminism is within fp32 tolerance).
__global__ __launch_bounds__(256) void fill_kernel(const int* __restrict__ src,
                                                   const int* __restrict__ dst,
                                                   const int* __restrict__ off,
                                                   int* __restrict__ deg,
                                                   int* __restrict__ ssrc, int E) {
    int e = blockIdx.x * 256 + threadIdx.x;
    if (e >= E) return;
    int d = dst[e];
    int pos = off[d] + atomicSub(&deg[d], 1) - 1;
    ssrc[pos] = src[e];
}

// ---------------- gather aggregation: one wave per dst node ----------------
// agg[node] = inv[node] * sum_{k in [off[node],off[node+1])} h[ssrc[k]]
template <int D>  // D = 128 (float2/lane) or 256 (float4/lane)
__global__ __launch_bounds__(256) void gather_agg(const float* __restrict__ h,
                                                  const int* __restrict__ off,
                                                  const int* __restrict__ ssrc,
                                                  const float* __restrict__ inv,
                                                  float* __restrict__ agg, int n) {
    int node = blockIdx.x * 4 + (threadIdx.x >> 6);
    if (node >= n) return;
    int lane = threadIdx.x & 63;
    int beg = off[node], end = off[node + 1];
    float sc = inv[node];

    if (D == 256) {
        const float* col = h + (lane << 2);
        float4 a0 = make_float4(0.f, 0.f, 0.f, 0.f);
        float4 a1 = make_float4(0.f, 0.f, 0.f, 0.f);
        int k = beg;
        for (; k + 1 < end; k += 2) {
            int s0 = ssrc[k], s1 = ssrc[k + 1];
            float4 v0 = *(const float4*)(col + (size_t)s0 * 256);
            float4 v1 = *(const float4*)(col + (size_t)s1 * 256);
            a0.x += v0.x; a0.y += v0.y; a0.z += v0.z; a0.w += v0.w;
            a1.x += v1.x; a1.y += v1.y; a1.z += v1.z; a1.w += v1.w;
        }
        if (k < end) {
            int s0 = ssrc[k];
            float4 v0 = *(const float4*)(col + (size_t)s0 * 256);
            a0.x += v0.x; a0.y += v0.y; a0.z += v0.z; a0.w += v0.w;
        }
        float4 r;
        r.x = (a0.x + a1.x) * sc;
        r.y = (a0.y + a1.y) * sc;
        r.z = (a0.z + a1.z) * sc;
        r.w = (a0.w + a1.w) * sc;
        *(float4*)(agg + (size_t)node * 256 + (lane << 2)) = r;
    } else {
        const float* col = h + (lane << 1);
        float2 a0 = make_float2(0.f, 0.f);
        float2 a1 = make_float2(0.f, 0.f);
        int k = beg;
        for (; k + 1 < end; k += 2) {
            int s0 = ssrc[k], s1 = ssrc[k + 1];
            float2 v0 = *(const float2*)(col + (size_t)s0 * 128);
            float2 v1 = *(const float2*)(col + (size_t)s1 * 128);
            a0.x += v0.x; a0.y += v0.y;
            a1.x += v1.x; a1.y += v1.y;
        }
        if (k < end) {
            int s0 = ssrc[k];
            float2 v0 = *(const float2*)(col + (size_t)s0 * 128);
            a0.x += v0.x; a0.y += v0.y;
        }
        float2 r;
        r.x = (a0.x + a1.x) * sc;
        r.y = (a0.y + a1.y) * sc;
        *(float2*)(agg + (size_t)node * 128 + (lane << 1)) = r;
    }
}

// ---------------- GEMM (unchanged from R0, minus row scaling) ----------------
// out[m][n] = act( A1[m,:] @ W1 + bias + A2[m,:] @ W2 ), A2/W2 optional.
__global__ __launch_bounds__(256) void gemm_sage(const float* __restrict__ A1,
                                                 const float* __restrict__ A2,
                                                 const float* __restrict__ W1,
                                                 const float* __restrict__ bias,
                                                 const float* __restrict__ W2,
                                                 float* __restrict__ out,
                                                 int M, int K, int Nn, int relu) {
    __shared__ __align__(16) float As[16][68];
    __shared__ __align__(16) float Bs[16][64];

    const int t  = threadIdx.x;
    const int tx = t & 15;
    const int ty = t >> 4;
    const int m0 = blockIdx.x * 64;
    const int n0 = blockIdx.y * 64;

    const int lrow = t >> 2;
    const int lk4  = (t & 3) << 2;
    const int brow = t >> 4;
    const int bcol = (t & 15) << 2;

    float c[4][4] = {};

    for (int pass = 0; pass < 2; ++pass) {
        const float* A = (pass == 0) ? A1 : A2;
        const float* W = (pass == 0) ? W1 : W2;
        if (pass == 1 && A2 == nullptr) break;

        for (int k0 = 0; k0 < K; k0 += 16) {
            {
                int gm = m0 + lrow;
                float4 v = make_float4(0.f, 0.f, 0.f, 0.f);
                if (gm < M) v = *(const float4*)(A + (size_t)gm * K + k0 + lk4);
                As[lk4 + 0][lrow] = v.x;
                As[lk4 + 1][lrow] = v.y;
                As[lk4 + 2][lrow] = v.z;
                As[lk4 + 3][lrow] = v.w;
            }
            {
                float4 v = *(const float4*)(W + (size_t)(k0 + brow) * Nn + n0 + bcol);
                *(float4*)&Bs[brow][bcol] = v;
            }
            __syncthreads();
#pragma unroll
            for (int kk = 0; kk < 16; ++kk) {
                float4 a = *(const float4*)&As[kk][ty << 2];
                float4 b = *(const float4*)&Bs[kk][tx << 2];
                c[0][0] = fmaf(a.x, b.x, c[0][0]);
                c[0][1] = fmaf(a.x, b.y, c[0][1]);
                c[0][2] = fmaf(a.x, b.z, c[0][2]);
                c[0][3] = fmaf(a.x, b.w, c[0][3]);
                c[1][0] = fmaf(a.y, b.x, c[1][0]);
                c[1][1] = fmaf(a.y, b.y, c[1][1]);
                c[1][2] = fmaf(a.y, b.z, c[1][2]);
                c[1][3] = fmaf(a.y, b.w, c[1][3]);
                c[2][0] = fmaf(a.z, b.x, c[2][0]);
                c[2][1] = fmaf(a.z, b.y, c[2][1]);
                c[2][2] = fmaf(a.z, b.z, c[2][2]);
                c[2][3] = fmaf(a.z, b.w, c[2][3]);
                c[3][0] = fmaf(a.w, b.x, c[3][0]);
                c[3][1] = fmaf(a.w, b.y, c[3][1]);
                c[3][2] = fmaf(a.w, b.z, c[3][2]);
                c[3][3] = fmaf(a.w, b.w, c[3][3]);
            }
            __syncthreads();
        }
    }

    float4 bv = make_float4(0.f, 0.f, 0.f, 0.f);
    if (bias != nullptr) bv = *(const float4*)(bias + n0 + (tx << 2));
#pragma unroll
    for (int i = 0; i < 4; ++i) {
        int gm = m0 + (ty << 2) + i;
        if (gm >= M) continue;
        float4 r;
        r.x = c[i][0] + bv.x;
        r.y = c[i][1] + bv.y;
        r.z = c[i][2] + bv.z;
        r.w = c[i][3] + bv.w;
        if (relu) {
            r.x = fmaxf(r.x, 0.f);
            r.y = fmaxf(r.y, 0.f);
            r.z = fmaxf(r.z, 0.f);
            r.w = fmaxf(r.w, 0.f);
        }
        *(float4*)(out + (size_t)gm * Nn + n0 + (tx << 2)) = r;
    }
}

// row-wise L2 normalize, rows of 256 floats; 4 rows per 256-thread block
__global__ __launch_bounds__(256) void norm_kernel(float* __restrict__ out, int M) {
    int row  = blockIdx.x * 4 + (threadIdx.x >> 6);
    int lane = threadIdx.x & 63;
    if (row >= M) return;
    float4 v = *(float4*)(out + (size_t)row * 256 + (lane << 2));
    float s = v.x * v.x + v.y * v.y + v.z * v.z + v.w * v.w;
#pragma unroll
    for (int off = 32; off > 0; off >>= 1) s += __shfl_down(s, off);
    s = __shfl(s, 0);
    float scale = 1.0f / fmaxf(sqrtf(s), 1e-12f);
    v.x *= scale; v.y *= scale; v.z *= scale; v.w *= scale;
    *(float4*)(out + (size_t)row * 256 + (lane << 2)) = v;
}

extern "C" void kernel_launch(void* const* d_in, const int* in_sizes, int n_in,
                              void* d_out, int out_size, void* d_ws, size_t ws_size,
                              hipStream_t stream) {
    const int N = 50000;
    const int E = 800000;
    const int NB = (N + 255) / 256;  // 196 scan blocks

    const float* x     = (const float*)d_in[0];
    const int*   ei    = (const int*)d_in[1];
    const float* pre_W = (const float*)d_in[2];
    const float* pre_b = (const float*)d_in[3];
    const float* W1_l  = (const float*)d_in[4];
    const float* b1    = (const float*)d_in[5];
    const float* W1_r  = (const float*)d_in[6];
    const float* W2_l  = (const float*)d_in[7];
    const float* b2    = (const float*)d_in[8];
    const float* W2_r  = (const float*)d_in[9];
    const float* W3_l  = (const float*)d_in[10];
    const float* b3    = (const float*)d_in[11];
    const float* W3_r  = (const float*)d_in[12];
    float* out = (float*)d_out;

    const int* src = ei;
    const int* dst = ei + E;

    // workspace: ints [deg N | off N+1 | bsum/boff 512 | ssrc E], then floats
    int* deg  = (int*)d_ws;
    int* off  = deg + N;
    int* bsum = off + N + 1;
    int* boff = bsum + 256;
    int* ssrc = boff + 256;
    size_t int_words = (size_t)2 * N + 1 + 512 + E;
    int_words = (int_words + 3) & ~(size_t)3;  // 16B align for float4 use

    float* inv  = (float*)d_ws + int_words;
    float* bufA = inv + N;                   // N*256: h0 | agg1; later agg2
    float* bufB = bufA + (size_t)N * 256;    // N*256: h1; later agg3
    float* bufC = bufB + (size_t)N * 256;    // N*256: h2

    float* h0   = bufA;
    float* agg1 = bufA + (size_t)N * 128;
    float* h1   = bufB;
    float* agg2 = bufA;   // h0/agg1 dead after GEMM1
    float* h2   = bufC;
    float* agg3 = bufB;   // h1 dead after GEMM2

    // ---- build CSR (counting sort by dst) ----
    hipMemsetAsync(deg, 0, (size_t)N * sizeof(int), stream);
    deg_kernel<<<(E + 255) / 256, 256, 0, stream>>>(dst, deg, E);
    bsum_kernel<<<NB, 256, 0, stream>>>(deg, bsum, N);
    bscan_kernel<<<1, 256, 0, stream>>>(bsum, boff, off, NB, N, E);
    scan_kernel<<<NB, 256, 0, stream>>>(deg, boff, off, inv, N);
    fill_kernel<<<(E + 255) / 256, 256, 0, stream>>>(src, dst, off, deg, ssrc, E);

    const int MT = (N + 63) / 64;
    const int AG = (N + 3) / 4;

    // ---- pre: h0 = x @ pre_W + pre_b ----
    gemm_sage<<<dim3(MT, 2), 256, 0, stream>>>(x, nullptr, pre_W, pre_b,
                                               nullptr, h0, N, 128, 128, 0);

    // ---- layer 1 ----
    gather_agg<128><<<AG, 256, 0, stream>>>(h0, off, ssrc, inv, agg1, N);
    gemm_sage<<<dim3(MT, 4), 256, 0, stream>>>(agg1, h0, W1_l, b1, W1_r,
                                               h1, N, 128, 256, 1);

    // ---- layer 2 ----
    gather_agg<256><<<AG, 256, 0, stream>>>(h1, off, ssrc, inv, agg2, N);
    gemm_sage<<<dim3(MT, 4), 256, 0, stream>>>(agg2, h1, W2_l, b2, W2_r,
                                               h2, N, 256, 256, 1);

    // ---- layer 3 (no relu), straight into d_out ----
    gather_agg<256><<<AG, 256, 0, stream>>>(h2, off, ssrc, inv, agg3, N);
    gemm_sage<<<dim3(MT, 4), 256, 0, stream>>>(agg3, h2, W3_l, b3, W3_r,
                                               out, N, 256, 256, 0);

    // ---- L2 normalize ----
    norm_kernel<<<AG, 256, 0, stream>>>(out, N);
}

// Round 6
// 547.879 us; speedup vs baseline: 4.2858x; 1.8754x over previous
//
#include <hip/hip_runtime.h>
#include <cstddef>
#include <cstdint>

// ---------------------------------------------------------------------------
// SAGE_89429809037918: pre-Linear(128->128) -> SAGEConv(128->256)+ReLU
//   -> SAGEConv(256->256)+ReLU -> SAGEConv(256->256) -> row L2-normalize.
// R5: resubmit of R4 (three container-level failures across two different
//     binaries => infra suspected, not kernel). bf16+MFMA pipeline, VGPR
//     staging (no global_load_lds). If this dies again, R6 = R1 canary.
// ---------------------------------------------------------------------------

typedef __attribute__((ext_vector_type(8))) short short8;   // 8 bf16 = 4 VGPR
typedef __attribute__((ext_vector_type(4))) float f32x4;

__device__ __forceinline__ unsigned rne_bf16(float f) {
    unsigned b = __float_as_uint(f);
    return (b + 0x7fffu + ((b >> 16) & 1u)) >> 16;
}
__device__ __forceinline__ float bf16_lo(unsigned u) { return __uint_as_float(u << 16); }
__device__ __forceinline__ float bf16_hi(unsigned u) { return __uint_as_float(u & 0xffff0000u); }

// ---------------- counting sort: histogram -> scan -> fill ----------------

__global__ __launch_bounds__(256) void deg_kernel(const int* __restrict__ dst,
                                                  int* __restrict__ deg, int E) {
    int e = blockIdx.x * 256 + threadIdx.x;
    if (e < E) atomicAdd(&deg[dst[e]], 1);
}

__global__ __launch_bounds__(256) void bsum_kernel(const int* __restrict__ deg,
                                                   int* __restrict__ bsum, int n) {
    int i = blockIdx.x * 256 + threadIdx.x;
    int v = (i < n) ? deg[i] : 0;
#pragma unroll
    for (int s = 32; s > 0; s >>= 1) v += __shfl_down(v, s);
    __shared__ int ws[4];
    int lane = threadIdx.x & 63, w = threadIdx.x >> 6;
    if (lane == 0) ws[w] = v;
    __syncthreads();
    if (threadIdx.x == 0) bsum[blockIdx.x] = ws[0] + ws[1] + ws[2] + ws[3];
}

__global__ __launch_bounds__(256) void bscan_kernel(const int* __restrict__ bsum,
                                                    int* __restrict__ boff,
                                                    int* __restrict__ off,
                                                    int nb, int n, int E) {
    int t = threadIdx.x;
    int v = (t < nb) ? bsum[t] : 0;
    int incl = v;
#pragma unroll
    for (int s = 1; s < 64; s <<= 1) {
        int u = __shfl_up(incl, s);
        if ((t & 63) >= s) incl += u;
    }
    __shared__ int ws[4];
    int lane = t & 63, w = t >> 6;
    if (lane == 63) ws[w] = incl;
    __syncthreads();
    int woff = 0;
    for (int j = 0; j < w; ++j) woff += ws[j];
    if (t < nb) boff[t] = woff + incl - v;
    if (t == 0) off[n] = E;
}

__global__ __launch_bounds__(256) void scan_kernel(const int* __restrict__ deg,
                                                   const int* __restrict__ boff,
                                                   int* __restrict__ off,
                                                   float* __restrict__ inv, int n) {
    int i = blockIdx.x * 256 + threadIdx.x;
    int v = (i < n) ? deg[i] : 0;
    int incl = v;
#pragma unroll
    for (int s = 1; s < 64; s <<= 1) {
        int u = __shfl_up(incl, s);
        if ((threadIdx.x & 63) >= s) incl += u;
    }
    __shared__ int ws[4];
    int lane = threadIdx.x & 63, w = threadIdx.x >> 6;
    if (lane == 63) ws[w] = incl;
    __syncthreads();
    int woff = 0;
    for (int j = 0; j < w; ++j) woff += ws[j];
    if (i < n) {
        off[i] = boff[blockIdx.x] + woff + incl - v;
        inv[i] = 1.0f / fmaxf((float)v, 1.0f);
    }
}

__global__ __launch_bounds__(256) void fill_kernel(const int* __restrict__ src,
                                                   const int* __restrict__ dst,
                                                   const int* __restrict__ off,
                                                   int* __restrict__ deg,
                                                   int* __restrict__ ssrc, int E) {
    int e = blockIdx.x * 256 + threadIdx.x;
    if (e >= E) return;
    int d = dst[e];
    int pos = off[d] + atomicSub(&deg[d], 1) - 1;
    ssrc[pos] = src[e];
}

// ---------------- one-shot converts: x -> bf16, W -> bf16 transposed --------

__global__ __launch_bounds__(256) void xconv(const float* __restrict__ x,
                                             uint2* __restrict__ xb, int n4) {
    int i = blockIdx.x * 256 + threadIdx.x;
    if (i >= n4) return;
    float4 v = ((const float4*)x)[i];
    uint2 o;
    o.x = rne_bf16(v.x) | (rne_bf16(v.y) << 16);
    o.y = rne_bf16(v.z) | (rne_bf16(v.w) << 16);
    xb[i] = o;
}

// W [K][Nn] fp32 -> WT [Nn][K] bf16, for all 7 weight matrices in one launch
__global__ __launch_bounds__(256) void wprep(
    const float* __restrict__ pre_W, const float* __restrict__ W1_l,
    const float* __restrict__ W1_r, const float* __restrict__ W2_l,
    const float* __restrict__ W2_r, const float* __restrict__ W3_l,
    const float* __restrict__ W3_r,
    unsigned short* __restrict__ WT0, unsigned short* __restrict__ WT1,
    unsigned short* __restrict__ WT2, unsigned short* __restrict__ WT3,
    unsigned short* __restrict__ WT4, unsigned short* __restrict__ WT5,
    unsigned short* __restrict__ WT6) {
    int idx = blockIdx.x * 256 + threadIdx.x;
    if (idx < 16384) {  // pre_W 128x128
        int k = idx >> 7, n = idx & 127;
        WT0[n * 128 + k] = (unsigned short)rne_bf16(pre_W[idx]);
        return;
    }
    idx -= 16384;
    if (idx < 32768) {  // W1_l 128x256
        int k = idx >> 8, n = idx & 255;
        WT1[n * 128 + k] = (unsigned short)rne_bf16(W1_l[idx]);
        return;
    }
    idx -= 32768;
    if (idx < 32768) {  // W1_r 128x256
        int k = idx >> 8, n = idx & 255;
        WT2[n * 128 + k] = (unsigned short)rne_bf16(W1_r[idx]);
        return;
    }
    idx -= 32768;
    if (idx < 65536) {  // W2_l 256x256
        int k = idx >> 8, n = idx & 255;
        WT3[n * 256 + k] = (unsigned short)rne_bf16(W2_l[idx]);
        return;
    }
    idx -= 65536;
    if (idx < 65536) {  // W2_r
        int k = idx >> 8, n = idx & 255;
        WT4[n * 256 + k] = (unsigned short)rne_bf16(W2_r[idx]);
        return;
    }
    idx -= 65536;
    if (idx < 65536) {  // W3_l
        int k = idx >> 8, n = idx & 255;
        WT5[n * 256 + k] = (unsigned short)rne_bf16(W3_l[idx]);
        return;
    }
    idx -= 65536;
    if (idx < 65536) {  // W3_r
        int k = idx >> 8, n = idx & 255;
        WT6[n * 256 + k] = (unsigned short)rne_bf16(W3_r[idx]);
    }
}

// ---------------- gather aggregation (bf16 in / bf16 out) ------------------

template <int D>
__global__ __launch_bounds__(256) void gather_b(const unsigned short* __restrict__ h,
                                                const int* __restrict__ off,
                                                const int* __restrict__ ssrc,
                                                const float* __restrict__ inv,
                                                unsigned short* __restrict__ agg, int n) {
    int node = blockIdx.x * 4 + (threadIdx.x >> 6);
    if (node >= n) return;
    int lane = threadIdx.x & 63;
    int beg = off[node], end = off[node + 1];
    float sc = inv[node];

    if (D == 256) {
        const unsigned short* col = h + (lane << 2);
        float a0 = 0, a1 = 0, a2 = 0, a3 = 0;
        float b0 = 0, b1 = 0, b2 = 0, b3 = 0;
        int k = beg;
        for (; k + 1 < end; k += 2) {
            int s0 = ssrc[k], s1 = ssrc[k + 1];
            uint2 u = *(const uint2*)(col + (size_t)s0 * 256);
            uint2 v = *(const uint2*)(col + (size_t)s1 * 256);
            a0 += bf16_lo(u.x); a1 += bf16_hi(u.x);
            a2 += bf16_lo(u.y); a3 += bf16_hi(u.y);
            b0 += bf16_lo(v.x); b1 += bf16_hi(v.x);
            b2 += bf16_lo(v.y); b3 += bf16_hi(v.y);
        }
        if (k < end) {
            uint2 u = *(const uint2*)(col + (size_t)ssrc[k] * 256);
            a0 += bf16_lo(u.x); a1 += bf16_hi(u.x);
            a2 += bf16_lo(u.y); a3 += bf16_hi(u.y);
        }
        a0 = (a0 + b0) * sc; a1 = (a1 + b1) * sc;
        a2 = (a2 + b2) * sc; a3 = (a3 + b3) * sc;
        uint2 o;
        o.x = rne_bf16(a0) | (rne_bf16(a1) << 16);
        o.y = rne_bf16(a2) | (rne_bf16(a3) << 16);
        *(uint2*)(agg + (size_t)node * 256 + (lane << 2)) = o;
    } else {
        const unsigned short* col = h + (lane << 1);
        float a0 = 0, a1 = 0, b0 = 0, b1 = 0;
        int k = beg;
        for (; k + 1 < end; k += 2) {
            int s0 = ssrc[k], s1 = ssrc[k + 1];
            unsigned u = *(const unsigned*)(col + (size_t)s0 * 128);
            unsigned v = *(const unsigned*)(col + (size_t)s1 * 128);
            a0 += bf16_lo(u); a1 += bf16_hi(u);
            b0 += bf16_lo(v); b1 += bf16_hi(v);
        }
        if (k < end) {
            unsigned u = *(const unsigned*)(col + (size_t)ssrc[k] * 128);
            a0 += bf16_lo(u); a1 += bf16_hi(u);
        }
        a0 = (a0 + b0) * sc; a1 = (a1 + b1) * sc;
        *(unsigned*)(agg + (size_t)node * 128 + (lane << 1)) =
            rne_bf16(a0) | (rne_bf16(a1) << 16);
    }
}

// ---------------- MFMA GEMM: out = act(A1@W1T^T + bias + A2@W2T^T) ---------
// A row-major bf16 [M,K]; WT row-major bf16 [Nn,K] (i.e. W transposed).
// Block tile 128x128, 4 waves 2x2 (64x64/wave = 4x4 frags of 16x16), BK=64.
// LDS slots XOR-swizzled (LDS slot s of row r holds global chunk s^(r&7))
// so ds_read_b128 on the fragment side is <=2-way bank-aliased (free).
__global__ __launch_bounds__(256) void gemm_bt(
    const unsigned short* __restrict__ A1, const unsigned short* __restrict__ W1T,
    const unsigned short* __restrict__ A2, const unsigned short* __restrict__ W2T,
    const float* __restrict__ bias,
    unsigned short* __restrict__ outb, float* __restrict__ outf,
    int M, int K, int Nn, int relu) {
    __shared__ __align__(16) unsigned short As[128 * 64];
    __shared__ __align__(16) unsigned short Bs[128 * 64];

    const int t = threadIdx.x;
    const int lane = t & 63;
    const int w = t >> 6;
    const int wm = w >> 1, wn = w & 1;
    const int m0 = blockIdx.x * 128;
    const int n0 = blockIdx.y * 128;

    f32x4 acc[4][4];
#pragma unroll
    for (int i = 0; i < 4; ++i)
#pragma unroll
        for (int j = 0; j < 4; ++j) acc[i][j] = (f32x4){0.f, 0.f, 0.f, 0.f};

    for (int pass = 0; pass < 2; ++pass) {
        const unsigned short* A = pass ? A2 : A1;
        const unsigned short* W = pass ? W2T : W1T;
        if (pass && A2 == nullptr) break;

        for (int k0 = 0; k0 < K; k0 += 64) {
            // stage 128x64 A-tile and B-tile: each thread moves 4x 16B chunks
#pragma unroll
            for (int r = 0; r < 4; ++r) {
                int p = r * 256 + t;          // LDS 16B-chunk index 0..1023
                int row = p >> 3, slot = p & 7;
                int c = slot ^ (row & 7);     // which global chunk lands here
                int gm = m0 + row;
                if (gm >= M) gm = M - 1;      // clamp; result rows >=M discarded
                uint4 va = *(const uint4*)(A + (size_t)gm * K + k0 + c * 8);
                uint4 vb = *(const uint4*)(W + (size_t)(n0 + row) * K + k0 + c * 8);
                *(uint4*)&As[(size_t)p * 8] = va;
                *(uint4*)&Bs[(size_t)p * 8] = vb;
            }
            __syncthreads();
#pragma unroll
            for (int kk = 0; kk < 2; ++kk) {
                short8 af[4], bfr[4];
                int ac = kk * 4 + (lane >> 4);
#pragma unroll
                for (int i = 0; i < 4; ++i) {
                    int arow = wm * 64 + i * 16 + (lane & 15);
                    af[i] = *(const short8*)&As[arow * 64 + ((ac ^ (arow & 7)) << 3)];
                    int brow = wn * 64 + i * 16 + (lane & 15);
                    bfr[i] = *(const short8*)&Bs[brow * 64 + ((ac ^ (brow & 7)) << 3)];
                }
#pragma unroll
                for (int mi = 0; mi < 4; ++mi)
#pragma unroll
                    for (int ni = 0; ni < 4; ++ni)
                        acc[mi][ni] = __builtin_amdgcn_mfma_f32_16x16x32_bf16(
                            af[mi], bfr[ni], acc[mi][ni], 0, 0, 0);
            }
            __syncthreads();
        }
    }

    // epilogue: C/D layout col(n)=lane&15, row(m)=(lane>>4)*4+reg
#pragma unroll
    for (int ni = 0; ni < 4; ++ni) {
        int n = n0 + wn * 64 + ni * 16 + (lane & 15);
        float bv = (bias != nullptr) ? bias[n] : 0.0f;
#pragma unroll
        for (int mi = 0; mi < 4; ++mi) {
            int mbase = m0 + wm * 64 + mi * 16 + ((lane >> 4) << 2);
#pragma unroll
            for (int r = 0; r < 4; ++r) {
                int m = mbase + r;
                if (m >= M) continue;
                float v = acc[mi][ni][r] + bv;
                if (relu) v = fmaxf(v, 0.0f);
                if (outb) outb[(size_t)m * Nn + n] = (unsigned short)rne_bf16(v);
                else      outf[(size_t)m * Nn + n] = v;
            }
        }
    }
}

// row-wise L2 normalize, rows of 256 floats; 4 rows per 256-thread block
__global__ __launch_bounds__(256) void norm_kernel(float* __restrict__ out, int M) {
    int row  = blockIdx.x * 4 + (threadIdx.x >> 6);
    int lane = threadIdx.x & 63;
    if (row >= M) return;
    float4 v = *(float4*)(out + (size_t)row * 256 + (lane << 2));
    float s = v.x * v.x + v.y * v.y + v.z * v.z + v.w * v.w;
#pragma unroll
    for (int off = 32; off > 0; off >>= 1) s += __shfl_down(s, off);
    s = __shfl(s, 0);
    float scale = 1.0f / fmaxf(sqrtf(s), 1e-12f);
    v.x *= scale; v.y *= scale; v.z *= scale; v.w *= scale;
    *(float4*)(out + (size_t)row * 256 + (lane << 2)) = v;
}

extern "C" void kernel_launch(void* const* d_in, const int* in_sizes, int n_in,
                              void* d_out, int out_size, void* d_ws, size_t ws_size,
                              hipStream_t stream) {
    const int N = 50000;
    const int E = 800000;
    const int NB = (N + 255) / 256;

    const float* x     = (const float*)d_in[0];
    const int*   ei    = (const int*)d_in[1];
    const float* pre_W = (const float*)d_in[2];
    const float* pre_b = (const float*)d_in[3];
    const float* W1_l  = (const float*)d_in[4];
    const float* b1    = (const float*)d_in[5];
    const float* W1_r  = (const float*)d_in[6];
    const float* W2_l  = (const float*)d_in[7];
    const float* b2    = (const float*)d_in[8];
    const float* W2_r  = (const float*)d_in[9];
    const float* W3_l  = (const float*)d_in[10];
    const float* b3    = (const float*)d_in[11];
    const float* W3_r  = (const float*)d_in[12];
    float* out = (float*)d_out;

    const int* src = ei;
    const int* dst = ei + E;

    // ---- workspace layout ----
    int* deg  = (int*)d_ws;
    int* off  = deg + N;
    int* bsum = off + N + 1;
    int* boff = bsum + 256;
    int* ssrc = boff + 256;
    size_t int_words = (size_t)2 * N + 1 + 512 + E;
    int_words = (int_words + 3) & ~(size_t)3;  // 16B align

    float* inv = (float*)d_ws + int_words;
    unsigned short* us = (unsigned short*)(inv + N);

    unsigned short* xb  = us;                 us += (size_t)N * 128;
    unsigned short* WT0 = us;                 us += 16384;
    unsigned short* WT1 = us;                 us += 32768;
    unsigned short* WT2 = us;                 us += 32768;
    unsigned short* WT3 = us;                 us += 65536;
    unsigned short* WT4 = us;                 us += 65536;
    unsigned short* WT5 = us;                 us += 65536;
    unsigned short* WT6 = us;                 us += 65536;
    unsigned short* h0b   = us;               us += (size_t)N * 128;
    unsigned short* agg1b = us;               us += (size_t)N * 128;
    unsigned short* h1b   = us;               us += (size_t)N * 256;
    unsigned short* agg2b = us;               us += (size_t)N * 256;
    unsigned short* h2b   = us;               us += (size_t)N * 256;
    unsigned short* agg3b = us;               us += (size_t)N * 256;

    // ---- build CSR (counting sort by dst) ----
    hipMemsetAsync(deg, 0, (size_t)N * sizeof(int), stream);
    deg_kernel<<<(E + 255) / 256, 256, 0, stream>>>(dst, deg, E);
    bsum_kernel<<<NB, 256, 0, stream>>>(deg, bsum, N);
    bscan_kernel<<<1, 256, 0, stream>>>(bsum, boff, off, NB, N, E);
    scan_kernel<<<NB, 256, 0, stream>>>(deg, boff, off, inv, N);
    fill_kernel<<<(E + 255) / 256, 256, 0, stream>>>(src, dst, off, deg, ssrc, E);

    // ---- converts ----
    xconv<<<(N * 128 / 4 + 255) / 256, 256, 0, stream>>>(x, (uint2*)xb, N * 128 / 4);
    wprep<<<(344064 + 255) / 256, 256, 0, stream>>>(pre_W, W1_l, W1_r, W2_l, W2_r,
                                                    W3_l, W3_r, WT0, WT1, WT2, WT3,
                                                    WT4, WT5, WT6);

    const int MT = (N + 127) / 128;  // 391
    const int AG = (N + 3) / 4;

    // ---- pre: h0 = x @ pre_W + pre_b ----
    gemm_bt<<<dim3(MT, 1), 256, 0, stream>>>(xb, WT0, nullptr, nullptr, pre_b,
                                             h0b, nullptr, N, 128, 128, 0);

    // ---- layer 1 ----
    gather_b<128><<<AG, 256, 0, stream>>>(h0b, off, ssrc, inv, agg1b, N);
    gemm_bt<<<dim3(MT, 2), 256, 0, stream>>>(agg1b, WT1, h0b, WT2, b1,
                                             h1b, nullptr, N, 128, 256, 1);

    // ---- layer 2 ----
    gather_b<256><<<AG, 256, 0, stream>>>(h1b, off, ssrc, inv, agg2b, N);
    gemm_bt<<<dim3(MT, 2), 256, 0, stream>>>(agg2b, WT3, h1b, WT4, b2,
                                             h2b, nullptr, N, 256, 256, 1);

    // ---- layer 3 (no relu), fp32 straight into d_out ----
    gather_b<256><<<AG, 256, 0, stream>>>(h2b, off, ssrc, inv, agg3b, N);
    gemm_bt<<<dim3(MT, 2), 256, 0, stream>>>(agg3b, WT5, h2b, WT6, b3,
                                             nullptr, out, N, 256, 256, 0);

    // ---- L2 normalize ----
    norm_kernel<<<AG, 256, 0, stream>>>(out, N);
}